// Round 3
// baseline (655.222 us; speedup 1.0000x reference)
//
#include <hip/hip_runtime.h>
#include <cstdint>
#include <cstddef>

// ---------------------------------------------------------------------------
// TensoSDF shape renderer: tri-plane sample + embed -> MLP(129->256->129)
// R4: fused kernel, three changes vs R3:
//  1. out[] stores are non-temporal (bypass LLC) -> stop evicting pl_t from
//     Infinity Cache; plane gathers become LLC hits (FETCH 372MB -> ~tens MB)
//  2. LDS union: mlp_in region (21.5KB, stride 168) aliases h region (32KB);
//     one extra barrier between layer-1 MFMA reads and h writes.
//     LDS = 32KB exactly -> 5 blocks/CU (was 3), 20 waves/CU.
//  3. mlp_in stride 168 halfs (84 dwords = 20 mod 32): rows 0..7 hit 8
//     distinct bank groups -> 16-row fragment reads are 2-way (free).
// Keeps: NCP=40 padded planes/lines (16B gathers), k-permuted w1/w2, f16 MFMA.
// ---------------------------------------------------------------------------

using half2v  = __attribute__((ext_vector_type(2))) _Float16;
using half4   = __attribute__((ext_vector_type(4))) _Float16;
using half8   = __attribute__((ext_vector_type(8))) _Float16;
using floatx4 = __attribute__((ext_vector_type(4))) float;

#define NPTS    524288
#define GRES    300
#define NCOMP   36
#define NCP     40
#define SDFD    256
#define IN_CH   129
#define OUT_CH  129
#define TILE_M  64
#define S_INL   168     // mlp_in LDS stride in halfs

// workspace layout (bytes), all 16B aligned
#define OFF_W1S 0
#define SZ_W1S  (5*4*256*8*2)               // 81920 : w1 swizzled f16 [c16][n=256][j=8]
#define OFF_W2S (OFF_W1S + SZ_W1S)
#define SZ_W2S  (8*4*144*8*2)               // 73728 : w2 swizzled f16
#define OFF_LT  (OFF_W2S + SZ_W2S)
#define SZ_LT   (3*GRES*NCP*2)              // 72000 : lines ch-last padded f16
#define OFF_PLT (OFF_LT + SZ_LT)
#define SZ_PLT  ((size_t)3*GRES*GRES*NCP*2) // 21.6MB: planes ch-last padded f16
#define NEED_FAST ((size_t)OFF_PLT + SZ_PLT)

// ---- prep kernels ---------------------------------------------------------

__global__ void prep_planes_k(const float* __restrict__ planes, _Float16* __restrict__ pl_t) {
    int idx = blockIdx.x * 256 + threadIdx.x;           // (m*300+y)*300+x
    if (idx >= 3 * GRES * GRES) return;
    int x = idx % GRES; int t = idx / GRES; int y = t % GRES; int m = t / GRES;
    _Float16* dst = pl_t + (size_t)idx * NCP;
    const float* src = planes + (size_t)m * NCOMP * GRES * GRES + (size_t)y * GRES + x;
    #pragma unroll
    for (int j = 0; j < 5; ++j) {
        half8 o;
        #pragma unroll
        for (int e = 0; e < 8; ++e) {
            int c = j * 8 + e;
            o[e] = (c < NCOMP) ? (_Float16)src[(size_t)c * GRES * GRES] : (_Float16)0.f;
        }
        *(half8*)(dst + j * 8) = o;
    }
}

#define NB_W1 ((5*4*256*8 + 255)/256)      // 160
#define NB_W2 ((8*4*144*8 + 255)/256)      // 144
#define NB_L  ((3*GRES + 255)/256)         // 4
__global__ void prep_small_k(const float* __restrict__ w1, const float* __restrict__ w2,
                             const float* __restrict__ lines,
                             _Float16* __restrict__ w1s, _Float16* __restrict__ w2s,
                             _Float16* __restrict__ l_t) {
    int b = blockIdx.x;
    if (b < NB_W1) {
        int t = b * 256 + threadIdx.x;                   // < 40960 exactly
        int j = t & 7; int n = (t >> 3) & 255; int q = t >> 11;
        int k = q * 8 + j;                               // 0..159
        float v = 0.f;
        if (k < 120) {
            int m = k / 40, c = k % 40;
            if (c < NCOMP) v = w1[n * IN_CH + 21 + m * NCOMP + c];
        } else if (k < 141) {
            v = w1[n * IN_CH + (k - 120)];
        }
        w1s[t] = (_Float16)v;
    } else if (b < NB_W1 + NB_W2) {
        int t = (b - NB_W1) * 256 + threadIdx.x;
        if (t >= 8*4*144*8) return;
        int j = t & 7; int r = t >> 3; int n = r % 144; int q = r / 144;
        int k = q * 8 + j;                               // 0..255
        float v = (n < OUT_CH) ? w2[n * SDFD + k] : 0.f;
        w2s[t] = (_Float16)v;
    } else {
        int idx = (b - NB_W1 - NB_W2) * 256 + threadIdx.x;   // m*300+z
        if (idx >= 3 * GRES) return;
        int z = idx % GRES; int m = idx / GRES;
        _Float16* dst = l_t + (size_t)idx * NCP;
        const float* src = lines + ((size_t)m * NCOMP) * GRES + z;
        #pragma unroll
        for (int c = 0; c < NCOMP; ++c) dst[c] = (_Float16)src[(size_t)c * GRES];
        dst[36] = dst[37] = dst[38] = dst[39] = (_Float16)0.f;
    }
}

// ---- device helpers -------------------------------------------------------

__device__ __forceinline__ float softplus100(float z) {
    return fmaxf(z, 0.f) + __logf(1.f + __expf(-fabsf(z)));
}

__device__ __forceinline__ void plane_coords(int m, float X, float Y, float Z,
                                             int& x0, int& y0, int& z0,
                                             float& tx, float& ty, float& tz) {
    const float px = (m == 2) ? Y : X;
    const float py = (m == 0) ? Y : Z;
    const float pz = (m == 0) ? Z : ((m == 1) ? Y : X);
    float fx = (px + 1.f) * 0.5f * 299.f;
    float fy = (py + 1.f) * 0.5f * 299.f;
    float fz = (pz + 1.f) * 0.5f * 299.f;
    x0 = (int)floorf(fx); x0 = x0 < 0 ? 0 : (x0 > 298 ? 298 : x0);
    y0 = (int)floorf(fy); y0 = y0 < 0 ? 0 : (y0 > 298 ? 298 : y0);
    z0 = (int)floorf(fz); z0 = z0 < 0 ? 0 : (z0 > 298 ? 298 : z0);
    tx = fx - (float)x0; ty = fy - (float)y0; tz = fz - (float)z0;
}

// fast gather: NCP=40 channel-last layout; corner-pair = 160B contiguous
__device__ __forceinline__ void plane_gather_fast(
    int m, float X, float Y, float Z,
    const _Float16* __restrict__ pl_t, const _Float16* __restrict__ l_t,
    half8 f[5])
{
    int x0, y0, z0; float tx, ty, tz;
    plane_coords(m, X, Y, Z, x0, y0, z0, tx, ty, tz);
    const _Float16 h00 = (_Float16)((1.f - tx) * (1.f - ty));
    const _Float16 h01 = (_Float16)(tx * (1.f - ty));
    const _Float16 h10 = (_Float16)((1.f - tx) * ty);
    const _Float16 h11 = (_Float16)(tx * ty);
    const _Float16 hl0 = (_Float16)(1.f - tz), hl1 = (_Float16)tz;
    const half8 W00 = {h00,h00,h00,h00,h00,h00,h00,h00};
    const half8 W01 = {h01,h01,h01,h01,h01,h01,h01,h01};
    const half8 W10 = {h10,h10,h10,h10,h10,h10,h10,h10};
    const half8 W11 = {h11,h11,h11,h11,h11,h11,h11,h11};
    const half8 WL0 = {hl0,hl0,hl0,hl0,hl0,hl0,hl0,hl0};
    const half8 WL1 = {hl1,hl1,hl1,hl1,hl1,hl1,hl1,hl1};
    const _Float16* r0 = pl_t + ((size_t)(m * GRES + y0) * GRES + x0) * NCP;  // (y0,x0|x0+1)
    const _Float16* r1 = r0 + (size_t)GRES * NCP;                              // (y0+1, ...)
    const _Float16* lb = l_t + (size_t)(m * GRES + z0) * NCP;                  // (z0|z0+1)
    half8 a0[10], a1[10], al[10];
    #pragma unroll
    for (int j = 0; j < 10; ++j) a0[j] = *(const half8*)(r0 + 8 * j);
    #pragma unroll
    for (int j = 0; j < 10; ++j) a1[j] = *(const half8*)(r1 + 8 * j);
    half8 pf[5];
    #pragma unroll
    for (int j = 0; j < 5; ++j)
        pf[j] = a0[j] * W00 + a0[j + 5] * W01 + a1[j] * W10 + a1[j + 5] * W11;
    #pragma unroll
    for (int j = 0; j < 10; ++j) al[j] = *(const half8*)(lb + 8 * j);
    #pragma unroll
    for (int j = 0; j < 5; ++j) {
        half8 lf = al[j] * WL0 + al[j + 5] * WL1;
        f[j] = pf[j] * lf;
    }
}

// slow gather: raw f32 planes/lines (fallback when workspace too small)
__device__ __forceinline__ void plane_gather_slow(
    int m, float X, float Y, float Z,
    const float* __restrict__ planes, const float* __restrict__ lines,
    half8 f[5])
{
    int x0, y0, z0; float tx, ty, tz;
    plane_coords(m, X, Y, Z, x0, y0, z0, tx, ty, tz);
    const float w00 = (1.f - tx) * (1.f - ty), w01 = tx * (1.f - ty);
    const float w10 = (1.f - tx) * ty,         w11 = tx * ty;
    const float lw0 = 1.f - tz, lw1 = tz;
    #pragma unroll
    for (int j = 0; j < 5; ++j) f[j] = (half8){0,0,0,0,0,0,0,0};
    const float* pb = planes + (size_t)m * NCOMP * GRES * GRES;
    #pragma unroll
    for (int c = 0; c < NCOMP; ++c) {
        const float* pc = pb + (size_t)c * GRES * GRES + (size_t)y0 * GRES + x0;
        const float* lc = lines + ((size_t)m * NCOMP + c) * GRES + z0;
        float pf = pc[0] * w00 + pc[1] * w01 + pc[GRES] * w10 + pc[GRES + 1] * w11;
        float lf = lc[0] * lw0 + lc[1] * lw1;
        f[c >> 3][c & 7] = (_Float16)(pf * lf);
    }
}

// embed -> chunks c16=15..19 (k=120..159); zeros beyond k=140
__device__ __forceinline__ void embed_chunks(float X, float Y, float Z, half8 e[5]) {
    const float v3[3] = {X, Y, Z};
    _Float16 s[3][3], c[3][3];
    #pragma unroll
    for (int d = 0; d < 3; ++d) {
        float fm = 1.f;
        #pragma unroll
        for (int q = 0; q < 3; ++q) {
            const float a = v3[d] * fm;
            s[d][q] = (_Float16)__sinf(a);
            c[d][q] = (_Float16)__cosf(a);
            fm *= 2.f;
        }
    }
    const _Float16 z0 = (_Float16)0.f;
    e[0] = (half8){(_Float16)X, (_Float16)Y, (_Float16)Z, s[0][0], s[0][1], s[0][2], s[1][0], s[1][1]};
    e[1] = (half8){s[1][2], s[2][0], s[2][1], s[2][2], c[0][0], c[0][1], c[0][2], c[1][0]};
    e[2] = (half8){c[1][1], c[1][2], c[2][0], c[2][1], c[2][2], z0, z0, z0};
    e[3] = (half8){z0,z0,z0,z0,z0,z0,z0,z0};
    e[4] = (half8){z0,z0,z0,z0,z0,z0,z0,z0};
}

// ---- fused kernel ---------------------------------------------------------
// LDS: single 32KB union buffer.
//   region A (phase1/layer1): mlp_in [64][S_INL=168] f16, 21504B, no swizzle
//   region B (epilogue/layer2): h [64][256] f16 XOR-swz (row&7)<<3, 32768B
// -> exactly 5 blocks/CU (160KB), 20 waves/CU.

template <int FASTMODE>
__global__ __launch_bounds__(256, 5)
void tsdf_fused40_k(const float* __restrict__ xyz,
                    const float* __restrict__ planes, const float* __restrict__ lines,
                    const _Float16* __restrict__ pl_t, const _Float16* __restrict__ l_t,
                    const _Float16* __restrict__ w1s, const _Float16* __restrict__ w2s,
                    const float* __restrict__ b1, const float* __restrict__ b2,
                    float* __restrict__ out)
{
    __shared__ _Float16 lds_u[TILE_M * 256];           // 32768 B union
    _Float16* mlp_lds = lds_u;                         // [64][S_INL]
    _Float16* h_lds   = lds_u;                         // [64][256] swz
    const int tid = threadIdx.x, blk = blockIdx.x;

    // ---------------- phase 1: sampling + embed into LDS -------------------
    {
        const int p = tid >> 2, sub = tid & 3;
        const size_t gp = (size_t)blk * TILE_M + p;
        const float X = xyz[gp * 3 + 0];
        const float Y = xyz[gp * 3 + 1];
        const float Z = xyz[gp * 3 + 2];
        half8 f[5];
        int c0;
        if (sub < 3) {
            if (FASTMODE) plane_gather_fast(sub, X, Y, Z, pl_t, l_t, f);
            else          plane_gather_slow(sub, X, Y, Z, planes, lines, f);
            c0 = sub * 5;
        } else {
            embed_chunks(X, Y, Z, f);
            c0 = 15;
        }
        #pragma unroll
        for (int j = 0; j < 5; ++j)
            *(half8*)&mlp_lds[p * S_INL + (c0 + j) * 8] = f[j];
    }
    __syncthreads();

    const int lane = tid & 63, wv = tid >> 6, l15 = lane & 15, quad = lane >> 4;

    // ---------------- layer 1: [64x160] @ [160x256] -> h -------------------
    floatx4 acc1[4][4];
    #pragma unroll
    for (int mt = 0; mt < 4; ++mt)
        #pragma unroll
        for (int nt = 0; nt < 4; ++nt)
            acc1[mt][nt] = (floatx4){0.f, 0.f, 0.f, 0.f};

    #pragma unroll
    for (int s = 0; s < 5; ++s) {
        half8 a[4], b[4];
        #pragma unroll
        for (int mt = 0; mt < 4; ++mt)
            a[mt] = *(const half8*)&mlp_lds[(mt * 16 + l15) * S_INL + s * 32 + quad * 8];
        #pragma unroll
        for (int nt = 0; nt < 4; ++nt)
            b[nt] = *(const half8*)(w1s + ((size_t)((s * 4 + quad) * 256) + wv * 64 + nt * 16 + l15) * 8);
        #pragma unroll
        for (int mt = 0; mt < 4; ++mt)
            #pragma unroll
            for (int nt = 0; nt < 4; ++nt)
                acc1[mt][nt] = __builtin_amdgcn_mfma_f32_16x16x32_f16(a[mt], b[nt], acc1[mt][nt], 0, 0, 0);
    }
    // all mlp_lds reads done; barrier before overwriting the union with h
    __syncthreads();

    // epilogue: softplus(100z)/100, write h (f16) to swizzled LDS
    #pragma unroll
    for (int nt = 0; nt < 4; ++nt) {
        const int n = wv * 64 + nt * 16 + l15;
        const float bias = b1[n];
        #pragma unroll
        for (int mt = 0; mt < 4; ++mt) {
            #pragma unroll
            for (int r = 0; r < 4; ++r) {
                const int rowh = mt * 16 + quad * 4 + r;
                const float z = 100.f * (acc1[mt][nt][r] + bias);
                h_lds[(rowh * 256 + n) ^ ((rowh & 7) << 3)] = (_Float16)(softplus100(z) * 0.01f);
            }
        }
    }
    __syncthreads();

    // ---------------- layer 2: [64x256] @ [256x144] -> out -----------------
    floatx4 acc2[9];
    #pragma unroll
    for (int nt = 0; nt < 9; ++nt) acc2[nt] = (floatx4){0.f, 0.f, 0.f, 0.f};

    const int row2 = wv * 16 + l15;
    #pragma unroll
    for (int s = 0; s < 8; ++s) {
        const half8 a = *(const half8*)&h_lds[(row2 * 256 + s * 32 + quad * 8) ^ ((row2 & 7) << 3)];
        #pragma unroll
        for (int nt = 0; nt < 9; ++nt) {
            const half8 b = *(const half8*)(w2s + ((size_t)((s * 4 + quad) * 144) + nt * 16 + l15) * 8);
            acc2[nt] = __builtin_amdgcn_mfma_f32_16x16x32_f16(a, b, acc2[nt], 0, 0, 0);
        }
    }
    const int m_lo = wv * 16 + quad * 4;
    #pragma unroll
    for (int nt = 0; nt < 9; ++nt) {
        const int n = nt * 16 + l15;
        if (n < OUT_CH) {
            const float bias = b2[n];
            #pragma unroll
            for (int r = 0; r < 4; ++r) {
                const size_t gm = (size_t)blk * TILE_M + m_lo + r;
                __builtin_nontemporal_store(acc2[nt][r] + bias, &out[gm * OUT_CH + n]);
            }
        }
    }
}

// ---- launch ---------------------------------------------------------------

extern "C" void kernel_launch(void* const* d_in, const int* in_sizes, int n_in,
                              void* d_out, int out_size, void* d_ws, size_t ws_size,
                              hipStream_t stream) {
    const float* xyz    = (const float*)d_in[0];
    const float* planes = (const float*)d_in[1];
    const float* lines  = (const float*)d_in[2];
    const float* w1     = (const float*)d_in[3];
    const float* b1     = (const float*)d_in[4];
    const float* w2     = (const float*)d_in[5];
    const float* b2     = (const float*)d_in[6];
    float* out = (float*)d_out;
    char* ws = (char*)d_ws;

    _Float16* w1s  = (_Float16*)(ws + OFF_W1S);
    _Float16* w2s  = (_Float16*)(ws + OFF_W2S);
    _Float16* l_t  = (_Float16*)(ws + OFF_LT);
    _Float16* pl_t = (_Float16*)(ws + OFF_PLT);

    const bool fast = (ws_size >= NEED_FAST);

    prep_small_k<<<NB_W1 + NB_W2 + NB_L, 256, 0, stream>>>(w1, w2, lines, w1s, w2s, l_t);

    if (fast) {
        prep_planes_k<<<(3 * GRES * GRES + 255) / 256, 256, 0, stream>>>(planes, pl_t);
        tsdf_fused40_k<1><<<NPTS / TILE_M, 256, 0, stream>>>(
            xyz, planes, lines, pl_t, l_t, w1s, w2s, b1, b2, out);
    } else {
        tsdf_fused40_k<0><<<NPTS / TILE_M, 256, 0, stream>>>(
            xyz, planes, lines, pl_t, l_t, w1s, w2s, b1, b2, out);
    }
}

// Round 4
// 603.851 us; speedup vs baseline: 1.0851x; 1.0851x over previous
//
#include <hip/hip_runtime.h>
#include <cstdint>
#include <cstddef>

// ---------------------------------------------------------------------------
// TensoSDF shape renderer: tri-plane sample + embed -> MLP(129->256->129)
// R5: consolidation. R4 post-mortem: NT stores caused 3.5x write amplification
// (921MB) -> reverted to normal stores; __launch_bounds__(256,5) strangled
// VGPRs to 48 (gather needs ~30 in-flight 16B loads) -> bounds(256,4) lets
// the allocator keep ~84-100 VGPRs while LDS (32KB union, exactly 160KB/5)
// still admits 5 blocks/CU.
// Keeps: NCP=40 padded planes/lines (16B gathers), k-permuted w1/w2,
//        LDS union (mlp_in stride-168 aliases h, extra barrier), f16 MFMA.
// ---------------------------------------------------------------------------

using half2v  = __attribute__((ext_vector_type(2))) _Float16;
using half4   = __attribute__((ext_vector_type(4))) _Float16;
using half8   = __attribute__((ext_vector_type(8))) _Float16;
using floatx4 = __attribute__((ext_vector_type(4))) float;

#define NPTS    524288
#define GRES    300
#define NCOMP   36
#define NCP     40
#define SDFD    256
#define IN_CH   129
#define OUT_CH  129
#define TILE_M  64
#define S_INL   168     // mlp_in LDS stride in halfs

// workspace layout (bytes), all 16B aligned
#define OFF_W1S 0
#define SZ_W1S  (5*4*256*8*2)               // 81920 : w1 swizzled f16 [c16][n=256][j=8]
#define OFF_W2S (OFF_W1S + SZ_W1S)
#define SZ_W2S  (8*4*144*8*2)               // 73728 : w2 swizzled f16
#define OFF_LT  (OFF_W2S + SZ_W2S)
#define SZ_LT   (3*GRES*NCP*2)              // 72000 : lines ch-last padded f16
#define OFF_PLT (OFF_LT + SZ_LT)
#define SZ_PLT  ((size_t)3*GRES*GRES*NCP*2) // 21.6MB: planes ch-last padded f16
#define NEED_FAST ((size_t)OFF_PLT + SZ_PLT)

// ---- prep kernels ---------------------------------------------------------

__global__ void prep_planes_k(const float* __restrict__ planes, _Float16* __restrict__ pl_t) {
    int idx = blockIdx.x * 256 + threadIdx.x;           // (m*300+y)*300+x
    if (idx >= 3 * GRES * GRES) return;
    int x = idx % GRES; int t = idx / GRES; int y = t % GRES; int m = t / GRES;
    _Float16* dst = pl_t + (size_t)idx * NCP;
    const float* src = planes + (size_t)m * NCOMP * GRES * GRES + (size_t)y * GRES + x;
    #pragma unroll
    for (int j = 0; j < 5; ++j) {
        half8 o;
        #pragma unroll
        for (int e = 0; e < 8; ++e) {
            int c = j * 8 + e;
            o[e] = (c < NCOMP) ? (_Float16)src[(size_t)c * GRES * GRES] : (_Float16)0.f;
        }
        *(half8*)(dst + j * 8) = o;
    }
}

#define NB_W1 ((5*4*256*8 + 255)/256)      // 160
#define NB_W2 ((8*4*144*8 + 255)/256)      // 144
#define NB_L  ((3*GRES + 255)/256)         // 4
__global__ void prep_small_k(const float* __restrict__ w1, const float* __restrict__ w2,
                             const float* __restrict__ lines,
                             _Float16* __restrict__ w1s, _Float16* __restrict__ w2s,
                             _Float16* __restrict__ l_t) {
    int b = blockIdx.x;
    if (b < NB_W1) {
        int t = b * 256 + threadIdx.x;                   // < 40960 exactly
        int j = t & 7; int n = (t >> 3) & 255; int q = t >> 11;
        int k = q * 8 + j;                               // 0..159
        float v = 0.f;
        if (k < 120) {
            int m = k / 40, c = k % 40;
            if (c < NCOMP) v = w1[n * IN_CH + 21 + m * NCOMP + c];
        } else if (k < 141) {
            v = w1[n * IN_CH + (k - 120)];
        }
        w1s[t] = (_Float16)v;
    } else if (b < NB_W1 + NB_W2) {
        int t = (b - NB_W1) * 256 + threadIdx.x;
        if (t >= 8*4*144*8) return;
        int j = t & 7; int r = t >> 3; int n = r % 144; int q = r / 144;
        int k = q * 8 + j;                               // 0..255
        float v = (n < OUT_CH) ? w2[n * SDFD + k] : 0.f;
        w2s[t] = (_Float16)v;
    } else {
        int idx = (b - NB_W1 - NB_W2) * 256 + threadIdx.x;   // m*300+z
        if (idx >= 3 * GRES) return;
        int z = idx % GRES; int m = idx / GRES;
        _Float16* dst = l_t + (size_t)idx * NCP;
        const float* src = lines + ((size_t)m * NCOMP) * GRES + z;
        #pragma unroll
        for (int c = 0; c < NCOMP; ++c) dst[c] = (_Float16)src[(size_t)c * GRES];
        dst[36] = dst[37] = dst[38] = dst[39] = (_Float16)0.f;
    }
}

// ---- device helpers -------------------------------------------------------

__device__ __forceinline__ float softplus100(float z) {
    return fmaxf(z, 0.f) + __logf(1.f + __expf(-fabsf(z)));
}

__device__ __forceinline__ void plane_coords(int m, float X, float Y, float Z,
                                             int& x0, int& y0, int& z0,
                                             float& tx, float& ty, float& tz) {
    const float px = (m == 2) ? Y : X;
    const float py = (m == 0) ? Y : Z;
    const float pz = (m == 0) ? Z : ((m == 1) ? Y : X);
    float fx = (px + 1.f) * 0.5f * 299.f;
    float fy = (py + 1.f) * 0.5f * 299.f;
    float fz = (pz + 1.f) * 0.5f * 299.f;
    x0 = (int)floorf(fx); x0 = x0 < 0 ? 0 : (x0 > 298 ? 298 : x0);
    y0 = (int)floorf(fy); y0 = y0 < 0 ? 0 : (y0 > 298 ? 298 : y0);
    z0 = (int)floorf(fz); z0 = z0 < 0 ? 0 : (z0 > 298 ? 298 : z0);
    tx = fx - (float)x0; ty = fy - (float)y0; tz = fz - (float)z0;
}

// fast gather: NCP=40 channel-last layout; corner-pair = 160B contiguous
__device__ __forceinline__ void plane_gather_fast(
    int m, float X, float Y, float Z,
    const _Float16* __restrict__ pl_t, const _Float16* __restrict__ l_t,
    half8 f[5])
{
    int x0, y0, z0; float tx, ty, tz;
    plane_coords(m, X, Y, Z, x0, y0, z0, tx, ty, tz);
    const _Float16 h00 = (_Float16)((1.f - tx) * (1.f - ty));
    const _Float16 h01 = (_Float16)(tx * (1.f - ty));
    const _Float16 h10 = (_Float16)((1.f - tx) * ty);
    const _Float16 h11 = (_Float16)(tx * ty);
    const _Float16 hl0 = (_Float16)(1.f - tz), hl1 = (_Float16)tz;
    const half8 W00 = {h00,h00,h00,h00,h00,h00,h00,h00};
    const half8 W01 = {h01,h01,h01,h01,h01,h01,h01,h01};
    const half8 W10 = {h10,h10,h10,h10,h10,h10,h10,h10};
    const half8 W11 = {h11,h11,h11,h11,h11,h11,h11,h11};
    const half8 WL0 = {hl0,hl0,hl0,hl0,hl0,hl0,hl0,hl0};
    const half8 WL1 = {hl1,hl1,hl1,hl1,hl1,hl1,hl1,hl1};
    const _Float16* r0 = pl_t + ((size_t)(m * GRES + y0) * GRES + x0) * NCP;  // (y0,x0|x0+1)
    const _Float16* r1 = r0 + (size_t)GRES * NCP;                              // (y0+1, ...)
    const _Float16* lb = l_t + (size_t)(m * GRES + z0) * NCP;                  // (z0|z0+1)
    half8 a0[10], a1[10], al[10];
    #pragma unroll
    for (int j = 0; j < 10; ++j) a0[j] = *(const half8*)(r0 + 8 * j);
    #pragma unroll
    for (int j = 0; j < 10; ++j) a1[j] = *(const half8*)(r1 + 8 * j);
    half8 pf[5];
    #pragma unroll
    for (int j = 0; j < 5; ++j)
        pf[j] = a0[j] * W00 + a0[j + 5] * W01 + a1[j] * W10 + a1[j + 5] * W11;
    #pragma unroll
    for (int j = 0; j < 10; ++j) al[j] = *(const half8*)(lb + 8 * j);
    #pragma unroll
    for (int j = 0; j < 5; ++j) {
        half8 lf = al[j] * WL0 + al[j + 5] * WL1;
        f[j] = pf[j] * lf;
    }
}

// slow gather: raw f32 planes/lines (fallback when workspace too small)
__device__ __forceinline__ void plane_gather_slow(
    int m, float X, float Y, float Z,
    const float* __restrict__ planes, const float* __restrict__ lines,
    half8 f[5])
{
    int x0, y0, z0; float tx, ty, tz;
    plane_coords(m, X, Y, Z, x0, y0, z0, tx, ty, tz);
    const float w00 = (1.f - tx) * (1.f - ty), w01 = tx * (1.f - ty);
    const float w10 = (1.f - tx) * ty,         w11 = tx * ty;
    const float lw0 = 1.f - tz, lw1 = tz;
    #pragma unroll
    for (int j = 0; j < 5; ++j) f[j] = (half8){0,0,0,0,0,0,0,0};
    const float* pb = planes + (size_t)m * NCOMP * GRES * GRES;
    #pragma unroll
    for (int c = 0; c < NCOMP; ++c) {
        const float* pc = pb + (size_t)c * GRES * GRES + (size_t)y0 * GRES + x0;
        const float* lc = lines + ((size_t)m * NCOMP + c) * GRES + z0;
        float pf = pc[0] * w00 + pc[1] * w01 + pc[GRES] * w10 + pc[GRES + 1] * w11;
        float lf = lc[0] * lw0 + lc[1] * lw1;
        f[c >> 3][c & 7] = (_Float16)(pf * lf);
    }
}

// embed -> chunks c16=15..19 (k=120..159); zeros beyond k=140
__device__ __forceinline__ void embed_chunks(float X, float Y, float Z, half8 e[5]) {
    const float v3[3] = {X, Y, Z};
    _Float16 s[3][3], c[3][3];
    #pragma unroll
    for (int d = 0; d < 3; ++d) {
        float fm = 1.f;
        #pragma unroll
        for (int q = 0; q < 3; ++q) {
            const float a = v3[d] * fm;
            s[d][q] = (_Float16)__sinf(a);
            c[d][q] = (_Float16)__cosf(a);
            fm *= 2.f;
        }
    }
    const _Float16 z0 = (_Float16)0.f;
    e[0] = (half8){(_Float16)X, (_Float16)Y, (_Float16)Z, s[0][0], s[0][1], s[0][2], s[1][0], s[1][1]};
    e[1] = (half8){s[1][2], s[2][0], s[2][1], s[2][2], c[0][0], c[0][1], c[0][2], c[1][0]};
    e[2] = (half8){c[1][1], c[1][2], c[2][0], c[2][1], c[2][2], z0, z0, z0};
    e[3] = (half8){z0,z0,z0,z0,z0,z0,z0,z0};
    e[4] = (half8){z0,z0,z0,z0,z0,z0,z0,z0};
}

// ---- fused kernel ---------------------------------------------------------
// LDS: single 32KB union buffer.
//   region A (phase1/layer1): mlp_in [64][S_INL=168] f16, 21504B
//   region B (epilogue/layer2): h [64][256] f16 XOR-swz (row&7)<<3, 32768B
// 5 blocks/CU requires VGPR<=102: bounds(256,4) caps at 128, natural ~84-100.
// (bounds(256,5) forced VGPR=48 in R4 -> gather ILP destroyed. Don't.)

template <int FASTMODE>
__global__ __launch_bounds__(256, 4)
void tsdf_fused40_k(const float* __restrict__ xyz,
                    const float* __restrict__ planes, const float* __restrict__ lines,
                    const _Float16* __restrict__ pl_t, const _Float16* __restrict__ l_t,
                    const _Float16* __restrict__ w1s, const _Float16* __restrict__ w2s,
                    const float* __restrict__ b1, const float* __restrict__ b2,
                    float* __restrict__ out)
{
    __shared__ _Float16 lds_u[TILE_M * 256];           // 32768 B union
    _Float16* mlp_lds = lds_u;                         // [64][S_INL]
    _Float16* h_lds   = lds_u;                         // [64][256] swz
    const int tid = threadIdx.x, blk = blockIdx.x;

    // ---------------- phase 1: sampling + embed into LDS -------------------
    {
        const int p = tid >> 2, sub = tid & 3;
        const size_t gp = (size_t)blk * TILE_M + p;
        const float X = xyz[gp * 3 + 0];
        const float Y = xyz[gp * 3 + 1];
        const float Z = xyz[gp * 3 + 2];
        half8 f[5];
        int c0;
        if (sub < 3) {
            if (FASTMODE) plane_gather_fast(sub, X, Y, Z, pl_t, l_t, f);
            else          plane_gather_slow(sub, X, Y, Z, planes, lines, f);
            c0 = sub * 5;
        } else {
            embed_chunks(X, Y, Z, f);
            c0 = 15;
        }
        #pragma unroll
        for (int j = 0; j < 5; ++j)
            *(half8*)&mlp_lds[p * S_INL + (c0 + j) * 8] = f[j];
    }
    __syncthreads();

    const int lane = tid & 63, wv = tid >> 6, l15 = lane & 15, quad = lane >> 4;

    // ---------------- layer 1: [64x160] @ [160x256] -> h -------------------
    floatx4 acc1[4][4];
    #pragma unroll
    for (int mt = 0; mt < 4; ++mt)
        #pragma unroll
        for (int nt = 0; nt < 4; ++nt)
            acc1[mt][nt] = (floatx4){0.f, 0.f, 0.f, 0.f};

    #pragma unroll
    for (int s = 0; s < 5; ++s) {
        half8 a[4], b[4];
        #pragma unroll
        for (int mt = 0; mt < 4; ++mt)
            a[mt] = *(const half8*)&mlp_lds[(mt * 16 + l15) * S_INL + s * 32 + quad * 8];
        #pragma unroll
        for (int nt = 0; nt < 4; ++nt)
            b[nt] = *(const half8*)(w1s + ((size_t)((s * 4 + quad) * 256) + wv * 64 + nt * 16 + l15) * 8);
        #pragma unroll
        for (int mt = 0; mt < 4; ++mt)
            #pragma unroll
            for (int nt = 0; nt < 4; ++nt)
                acc1[mt][nt] = __builtin_amdgcn_mfma_f32_16x16x32_f16(a[mt], b[nt], acc1[mt][nt], 0, 0, 0);
    }
    // all mlp_lds reads done; barrier before overwriting the union with h
    __syncthreads();

    // epilogue: softplus(100z)/100, write h (f16) to swizzled LDS
    #pragma unroll
    for (int nt = 0; nt < 4; ++nt) {
        const int n = wv * 64 + nt * 16 + l15;
        const float bias = b1[n];
        #pragma unroll
        for (int mt = 0; mt < 4; ++mt) {
            #pragma unroll
            for (int r = 0; r < 4; ++r) {
                const int rowh = mt * 16 + quad * 4 + r;
                const float z = 100.f * (acc1[mt][nt][r] + bias);
                h_lds[(rowh * 256 + n) ^ ((rowh & 7) << 3)] = (_Float16)(softplus100(z) * 0.01f);
            }
        }
    }
    __syncthreads();

    // ---------------- layer 2: [64x256] @ [256x144] -> out -----------------
    floatx4 acc2[9];
    #pragma unroll
    for (int nt = 0; nt < 9; ++nt) acc2[nt] = (floatx4){0.f, 0.f, 0.f, 0.f};

    const int row2 = wv * 16 + l15;
    #pragma unroll
    for (int s = 0; s < 8; ++s) {
        const half8 a = *(const half8*)&h_lds[(row2 * 256 + s * 32 + quad * 8) ^ ((row2 & 7) << 3)];
        #pragma unroll
        for (int nt = 0; nt < 9; ++nt) {
            const half8 b = *(const half8*)(w2s + ((size_t)((s * 4 + quad) * 144) + nt * 16 + l15) * 8);
            acc2[nt] = __builtin_amdgcn_mfma_f32_16x16x32_f16(a, b, acc2[nt], 0, 0, 0);
        }
    }
    const int m_lo = wv * 16 + quad * 4;
    #pragma unroll
    for (int nt = 0; nt < 9; ++nt) {
        const int n = nt * 16 + l15;
        if (n < OUT_CH) {
            const float bias = b2[n];
            #pragma unroll
            for (int r = 0; r < 4; ++r) {
                const size_t gm = (size_t)blk * TILE_M + m_lo + r;
                out[gm * OUT_CH + n] = acc2[nt][r] + bias;
            }
        }
    }
}

// ---- launch ---------------------------------------------------------------

extern "C" void kernel_launch(void* const* d_in, const int* in_sizes, int n_in,
                              void* d_out, int out_size, void* d_ws, size_t ws_size,
                              hipStream_t stream) {
    const float* xyz    = (const float*)d_in[0];
    const float* planes = (const float*)d_in[1];
    const float* lines  = (const float*)d_in[2];
    const float* w1     = (const float*)d_in[3];
    const float* b1     = (const float*)d_in[4];
    const float* w2     = (const float*)d_in[5];
    const float* b2     = (const float*)d_in[6];
    float* out = (float*)d_out;
    char* ws = (char*)d_ws;

    _Float16* w1s  = (_Float16*)(ws + OFF_W1S);
    _Float16* w2s  = (_Float16*)(ws + OFF_W2S);
    _Float16* l_t  = (_Float16*)(ws + OFF_LT);
    _Float16* pl_t = (_Float16*)(ws + OFF_PLT);

    const bool fast = (ws_size >= NEED_FAST);

    prep_small_k<<<NB_W1 + NB_W2 + NB_L, 256, 0, stream>>>(w1, w2, lines, w1s, w2s, l_t);

    if (fast) {
        prep_planes_k<<<(3 * GRES * GRES + 255) / 256, 256, 0, stream>>>(planes, pl_t);
        tsdf_fused40_k<1><<<NPTS / TILE_M, 256, 0, stream>>>(
            xyz, planes, lines, pl_t, l_t, w1s, w2s, b1, b2, out);
    } else {
        tsdf_fused40_k<0><<<NPTS / TILE_M, 256, 0, stream>>>(
            xyz, planes, lines, pl_t, l_t, w1s, w2s, b1, b2, out);
    }
}

// Round 5
// 568.576 us; speedup vs baseline: 1.1524x; 1.0620x over previous
//
#include <hip/hip_runtime.h>
#include <cstdint>
#include <cstddef>

// ---------------------------------------------------------------------------
// TensoSDF shape renderer: tri-plane sample + embed -> MLP(129->256->129)
// R6: consolidation of R3..R5 evidence.
//  - bounds(256,3): the allocator must keep >=84 VGPR for gather ILP
//    (R5's bounds(256,4) gave VGPR=64 -> serialized gather loads, slower
//    despite higher occupancy). LDS 32KB union still admits 4-5 blocks/CU
//    if VGPR <= 128; floor = R3's 3 blocks.
//  - out epilogue: stage cols 0..127 as f32 [64][128] (=32KB exactly, reuses
//    the dead union buffer), col 128 written directly; then burst-copy 8192
//    dwords coalesced. Kills the partial-line RMW amplification seen in R5
//    (WRITE 433MB, FETCH +120MB).
// Keeps: NCP=40 padded planes/lines (16B gathers), k-permuted w1/w2,
//        LDS union (mlp_in stride-168 aliases h), f16 MFMA.
// ---------------------------------------------------------------------------

using half2v  = __attribute__((ext_vector_type(2))) _Float16;
using half4   = __attribute__((ext_vector_type(4))) _Float16;
using half8   = __attribute__((ext_vector_type(8))) _Float16;
using floatx4 = __attribute__((ext_vector_type(4))) float;

#define NPTS    524288
#define GRES    300
#define NCOMP   36
#define NCP     40
#define SDFD    256
#define IN_CH   129
#define OUT_CH  129
#define TILE_M  64
#define S_INL   168     // mlp_in LDS stride in halfs

// workspace layout (bytes), all 16B aligned
#define OFF_W1S 0
#define SZ_W1S  (5*4*256*8*2)               // 81920 : w1 swizzled f16 [c16][n=256][j=8]
#define OFF_W2S (OFF_W1S + SZ_W1S)
#define SZ_W2S  (8*4*144*8*2)               // 73728 : w2 swizzled f16
#define OFF_LT  (OFF_W2S + SZ_W2S)
#define SZ_LT   (3*GRES*NCP*2)              // 72000 : lines ch-last padded f16
#define OFF_PLT (OFF_LT + SZ_LT)
#define SZ_PLT  ((size_t)3*GRES*GRES*NCP*2) // 21.6MB: planes ch-last padded f16
#define NEED_FAST ((size_t)OFF_PLT + SZ_PLT)

// ---- prep kernels ---------------------------------------------------------

__global__ void prep_planes_k(const float* __restrict__ planes, _Float16* __restrict__ pl_t) {
    int idx = blockIdx.x * 256 + threadIdx.x;           // (m*300+y)*300+x
    if (idx >= 3 * GRES * GRES) return;
    int x = idx % GRES; int t = idx / GRES; int y = t % GRES; int m = t / GRES;
    _Float16* dst = pl_t + (size_t)idx * NCP;
    const float* src = planes + (size_t)m * NCOMP * GRES * GRES + (size_t)y * GRES + x;
    #pragma unroll
    for (int j = 0; j < 5; ++j) {
        half8 o;
        #pragma unroll
        for (int e = 0; e < 8; ++e) {
            int c = j * 8 + e;
            o[e] = (c < NCOMP) ? (_Float16)src[(size_t)c * GRES * GRES] : (_Float16)0.f;
        }
        *(half8*)(dst + j * 8) = o;
    }
}

#define NB_W1 ((5*4*256*8 + 255)/256)      // 160
#define NB_W2 ((8*4*144*8 + 255)/256)      // 144
#define NB_L  ((3*GRES + 255)/256)         // 4
__global__ void prep_small_k(const float* __restrict__ w1, const float* __restrict__ w2,
                             const float* __restrict__ lines,
                             _Float16* __restrict__ w1s, _Float16* __restrict__ w2s,
                             _Float16* __restrict__ l_t) {
    int b = blockIdx.x;
    if (b < NB_W1) {
        int t = b * 256 + threadIdx.x;                   // < 40960 exactly
        int j = t & 7; int n = (t >> 3) & 255; int q = t >> 11;
        int k = q * 8 + j;                               // 0..159
        float v = 0.f;
        if (k < 120) {
            int m = k / 40, c = k % 40;
            if (c < NCOMP) v = w1[n * IN_CH + 21 + m * NCOMP + c];
        } else if (k < 141) {
            v = w1[n * IN_CH + (k - 120)];
        }
        w1s[t] = (_Float16)v;
    } else if (b < NB_W1 + NB_W2) {
        int t = (b - NB_W1) * 256 + threadIdx.x;
        if (t >= 8*4*144*8) return;
        int j = t & 7; int r = t >> 3; int n = r % 144; int q = r / 144;
        int k = q * 8 + j;                               // 0..255
        float v = (n < OUT_CH) ? w2[n * SDFD + k] : 0.f;
        w2s[t] = (_Float16)v;
    } else {
        int idx = (b - NB_W1 - NB_W2) * 256 + threadIdx.x;   // m*300+z
        if (idx >= 3 * GRES) return;
        int z = idx % GRES; int m = idx / GRES;
        _Float16* dst = l_t + (size_t)idx * NCP;
        const float* src = lines + ((size_t)m * NCOMP) * GRES + z;
        #pragma unroll
        for (int c = 0; c < NCOMP; ++c) dst[c] = (_Float16)src[(size_t)c * GRES];
        dst[36] = dst[37] = dst[38] = dst[39] = (_Float16)0.f;
    }
}

// ---- device helpers -------------------------------------------------------

__device__ __forceinline__ float softplus100(float z) {
    return fmaxf(z, 0.f) + __logf(1.f + __expf(-fabsf(z)));
}

__device__ __forceinline__ void plane_coords(int m, float X, float Y, float Z,
                                             int& x0, int& y0, int& z0,
                                             float& tx, float& ty, float& tz) {
    const float px = (m == 2) ? Y : X;
    const float py = (m == 0) ? Y : Z;
    const float pz = (m == 0) ? Z : ((m == 1) ? Y : X);
    float fx = (px + 1.f) * 0.5f * 299.f;
    float fy = (py + 1.f) * 0.5f * 299.f;
    float fz = (pz + 1.f) * 0.5f * 299.f;
    x0 = (int)floorf(fx); x0 = x0 < 0 ? 0 : (x0 > 298 ? 298 : x0);
    y0 = (int)floorf(fy); y0 = y0 < 0 ? 0 : (y0 > 298 ? 298 : y0);
    z0 = (int)floorf(fz); z0 = z0 < 0 ? 0 : (z0 > 298 ? 298 : z0);
    tx = fx - (float)x0; ty = fy - (float)y0; tz = fz - (float)z0;
}

// fast gather: NCP=40 channel-last layout; corner-pair = 160B contiguous
__device__ __forceinline__ void plane_gather_fast(
    int m, float X, float Y, float Z,
    const _Float16* __restrict__ pl_t, const _Float16* __restrict__ l_t,
    half8 f[5])
{
    int x0, y0, z0; float tx, ty, tz;
    plane_coords(m, X, Y, Z, x0, y0, z0, tx, ty, tz);
    const _Float16 h00 = (_Float16)((1.f - tx) * (1.f - ty));
    const _Float16 h01 = (_Float16)(tx * (1.f - ty));
    const _Float16 h10 = (_Float16)((1.f - tx) * ty);
    const _Float16 h11 = (_Float16)(tx * ty);
    const _Float16 hl0 = (_Float16)(1.f - tz), hl1 = (_Float16)tz;
    const half8 W00 = {h00,h00,h00,h00,h00,h00,h00,h00};
    const half8 W01 = {h01,h01,h01,h01,h01,h01,h01,h01};
    const half8 W10 = {h10,h10,h10,h10,h10,h10,h10,h10};
    const half8 W11 = {h11,h11,h11,h11,h11,h11,h11,h11};
    const half8 WL0 = {hl0,hl0,hl0,hl0,hl0,hl0,hl0,hl0};
    const half8 WL1 = {hl1,hl1,hl1,hl1,hl1,hl1,hl1,hl1};
    const _Float16* r0 = pl_t + ((size_t)(m * GRES + y0) * GRES + x0) * NCP;  // (y0,x0|x0+1)
    const _Float16* r1 = r0 + (size_t)GRES * NCP;                              // (y0+1, ...)
    const _Float16* lb = l_t + (size_t)(m * GRES + z0) * NCP;                  // (z0|z0+1)
    half8 a0[10], a1[10], al[10];
    #pragma unroll
    for (int j = 0; j < 10; ++j) a0[j] = *(const half8*)(r0 + 8 * j);
    #pragma unroll
    for (int j = 0; j < 10; ++j) a1[j] = *(const half8*)(r1 + 8 * j);
    half8 pf[5];
    #pragma unroll
    for (int j = 0; j < 5; ++j)
        pf[j] = a0[j] * W00 + a0[j + 5] * W01 + a1[j] * W10 + a1[j + 5] * W11;
    #pragma unroll
    for (int j = 0; j < 10; ++j) al[j] = *(const half8*)(lb + 8 * j);
    #pragma unroll
    for (int j = 0; j < 5; ++j) {
        half8 lf = al[j] * WL0 + al[j + 5] * WL1;
        f[j] = pf[j] * lf;
    }
}

// slow gather: raw f32 planes/lines (fallback when workspace too small)
__device__ __forceinline__ void plane_gather_slow(
    int m, float X, float Y, float Z,
    const float* __restrict__ planes, const float* __restrict__ lines,
    half8 f[5])
{
    int x0, y0, z0; float tx, ty, tz;
    plane_coords(m, X, Y, Z, x0, y0, z0, tx, ty, tz);
    const float w00 = (1.f - tx) * (1.f - ty), w01 = tx * (1.f - ty);
    const float w10 = (1.f - tx) * ty,         w11 = tx * ty;
    const float lw0 = 1.f - tz, lw1 = tz;
    #pragma unroll
    for (int j = 0; j < 5; ++j) f[j] = (half8){0,0,0,0,0,0,0,0};
    const float* pb = planes + (size_t)m * NCOMP * GRES * GRES;
    #pragma unroll
    for (int c = 0; c < NCOMP; ++c) {
        const float* pc = pb + (size_t)c * GRES * GRES + (size_t)y0 * GRES + x0;
        const float* lc = lines + ((size_t)m * NCOMP + c) * GRES + z0;
        float pf = pc[0] * w00 + pc[1] * w01 + pc[GRES] * w10 + pc[GRES + 1] * w11;
        float lf = lc[0] * lw0 + lc[1] * lw1;
        f[c >> 3][c & 7] = (_Float16)(pf * lf);
    }
}

// embed -> chunks c16=15..19 (k=120..159); zeros beyond k=140
__device__ __forceinline__ void embed_chunks(float X, float Y, float Z, half8 e[5]) {
    const float v3[3] = {X, Y, Z};
    _Float16 s[3][3], c[3][3];
    #pragma unroll
    for (int d = 0; d < 3; ++d) {
        float fm = 1.f;
        #pragma unroll
        for (int q = 0; q < 3; ++q) {
            const float a = v3[d] * fm;
            s[d][q] = (_Float16)__sinf(a);
            c[d][q] = (_Float16)__cosf(a);
            fm *= 2.f;
        }
    }
    const _Float16 z0 = (_Float16)0.f;
    e[0] = (half8){(_Float16)X, (_Float16)Y, (_Float16)Z, s[0][0], s[0][1], s[0][2], s[1][0], s[1][1]};
    e[1] = (half8){s[1][2], s[2][0], s[2][1], s[2][2], c[0][0], c[0][1], c[0][2], c[1][0]};
    e[2] = (half8){c[1][1], c[1][2], c[2][0], c[2][1], c[2][2], z0, z0, z0};
    e[3] = (half8){z0,z0,z0,z0,z0,z0,z0,z0};
    e[4] = (half8){z0,z0,z0,z0,z0,z0,z0,z0};
}

// ---- fused kernel ---------------------------------------------------------
// LDS: single 32KB union buffer, three lifetimes:
//   A (phase1/layer1): mlp_in [64][S_INL=168] f16, 21504B
//   B (epilogue1/layer2): h [64][256] f16 XOR-swz (row&7)<<3, 32768B
//   C (epilogue2): out stage [64][128] f32, 32768B
// bounds(256,3): VGPR cap 170 -> allocator keeps gather ILP (R3: 84).
// LDS admits 5 blocks/CU; actual = min(5, 512/VGPR).

template <int FASTMODE>
__global__ __launch_bounds__(256, 3)
void tsdf_fused40_k(const float* __restrict__ xyz,
                    const float* __restrict__ planes, const float* __restrict__ lines,
                    const _Float16* __restrict__ pl_t, const _Float16* __restrict__ l_t,
                    const _Float16* __restrict__ w1s, const _Float16* __restrict__ w2s,
                    const float* __restrict__ b1, const float* __restrict__ b2,
                    float* __restrict__ out)
{
    __shared__ _Float16 lds_u[TILE_M * 256];           // 32768 B union
    _Float16* mlp_lds = lds_u;                         // [64][S_INL]
    _Float16* h_lds   = lds_u;                         // [64][256] swz
    const int tid = threadIdx.x, blk = blockIdx.x;

    // ---------------- phase 1: sampling + embed into LDS -------------------
    {
        const int p = tid >> 2, sub = tid & 3;
        const size_t gp = (size_t)blk * TILE_M + p;
        const float X = xyz[gp * 3 + 0];
        const float Y = xyz[gp * 3 + 1];
        const float Z = xyz[gp * 3 + 2];
        half8 f[5];
        int c0;
        if (sub < 3) {
            if (FASTMODE) plane_gather_fast(sub, X, Y, Z, pl_t, l_t, f);
            else          plane_gather_slow(sub, X, Y, Z, planes, lines, f);
            c0 = sub * 5;
        } else {
            embed_chunks(X, Y, Z, f);
            c0 = 15;
        }
        #pragma unroll
        for (int j = 0; j < 5; ++j)
            *(half8*)&mlp_lds[p * S_INL + (c0 + j) * 8] = f[j];
    }
    __syncthreads();

    const int lane = tid & 63, wv = tid >> 6, l15 = lane & 15, quad = lane >> 4;

    // ---------------- layer 1: [64x160] @ [160x256] -> h -------------------
    floatx4 acc1[4][4];
    #pragma unroll
    for (int mt = 0; mt < 4; ++mt)
        #pragma unroll
        for (int nt = 0; nt < 4; ++nt)
            acc1[mt][nt] = (floatx4){0.f, 0.f, 0.f, 0.f};

    #pragma unroll
    for (int s = 0; s < 5; ++s) {
        half8 a[4], b[4];
        #pragma unroll
        for (int mt = 0; mt < 4; ++mt)
            a[mt] = *(const half8*)&mlp_lds[(mt * 16 + l15) * S_INL + s * 32 + quad * 8];
        #pragma unroll
        for (int nt = 0; nt < 4; ++nt)
            b[nt] = *(const half8*)(w1s + ((size_t)((s * 4 + quad) * 256) + wv * 64 + nt * 16 + l15) * 8);
        #pragma unroll
        for (int mt = 0; mt < 4; ++mt)
            #pragma unroll
            for (int nt = 0; nt < 4; ++nt)
                acc1[mt][nt] = __builtin_amdgcn_mfma_f32_16x16x32_f16(a[mt], b[nt], acc1[mt][nt], 0, 0, 0);
    }
    // all mlp_lds reads done; barrier before overwriting the union with h
    __syncthreads();

    // epilogue 1: softplus(100z)/100, write h (f16) to swizzled LDS
    #pragma unroll
    for (int nt = 0; nt < 4; ++nt) {
        const int n = wv * 64 + nt * 16 + l15;
        const float bias = b1[n];
        #pragma unroll
        for (int mt = 0; mt < 4; ++mt) {
            #pragma unroll
            for (int r = 0; r < 4; ++r) {
                const int rowh = mt * 16 + quad * 4 + r;
                const float z = 100.f * (acc1[mt][nt][r] + bias);
                h_lds[(rowh * 256 + n) ^ ((rowh & 7) << 3)] = (_Float16)(softplus100(z) * 0.01f);
            }
        }
    }
    __syncthreads();

    // ---------------- layer 2: [64x256] @ [256x144] -> out -----------------
    floatx4 acc2[9];
    #pragma unroll
    for (int nt = 0; nt < 9; ++nt) acc2[nt] = (floatx4){0.f, 0.f, 0.f, 0.f};

    const int row2 = wv * 16 + l15;
    #pragma unroll
    for (int s = 0; s < 8; ++s) {
        const half8 a = *(const half8*)&h_lds[(row2 * 256 + s * 32 + quad * 8) ^ ((row2 & 7) << 3)];
        #pragma unroll
        for (int nt = 0; nt < 9; ++nt) {
            const half8 b = *(const half8*)(w2s + ((size_t)((s * 4 + quad) * 144) + nt * 16 + l15) * 8);
            acc2[nt] = __builtin_amdgcn_mfma_f32_16x16x32_f16(a, b, acc2[nt], 0, 0, 0);
        }
    }

    // epilogue 2: stage cols 0..127 in LDS (reuse union), col 128 direct,
    // then burst-copy coalesced (full 128B lines, tight window -> no RMW).
    __syncthreads();                                   // all h reads done
    float* o_lds = (float*)lds_u;                      // [64][128] f32
    const int m_lo = wv * 16 + quad * 4;
    #pragma unroll
    for (int nt = 0; nt < 8; ++nt) {
        const int n = nt * 16 + l15;
        const float bias = b2[n];
        #pragma unroll
        for (int r = 0; r < 4; ++r)
            o_lds[(m_lo + r) * 128 + n] = acc2[nt][r] + bias;
    }
    if (l15 == 0) {
        const float b128 = b2[128];
        #pragma unroll
        for (int r = 0; r < 4; ++r)
            out[((size_t)blk * TILE_M + m_lo + r) * OUT_CH + 128] = acc2[8][r] + b128;
    }
    __syncthreads();
    const size_t obase = (size_t)blk * TILE_M;
    #pragma unroll
    for (int c = 0; c < 32; ++c) {
        const int idx = c * 256 + tid;                 // 0..8191
        const int row = idx >> 7, col = idx & 127;
        out[(obase + row) * OUT_CH + col] = o_lds[idx];
    }
}

// ---- launch ---------------------------------------------------------------

extern "C" void kernel_launch(void* const* d_in, const int* in_sizes, int n_in,
                              void* d_out, int out_size, void* d_ws, size_t ws_size,
                              hipStream_t stream) {
    const float* xyz    = (const float*)d_in[0];
    const float* planes = (const float*)d_in[1];
    const float* lines  = (const float*)d_in[2];
    const float* w1     = (const float*)d_in[3];
    const float* b1     = (const float*)d_in[4];
    const float* w2     = (const float*)d_in[5];
    const float* b2     = (const float*)d_in[6];
    float* out = (float*)d_out;
    char* ws = (char*)d_ws;

    _Float16* w1s  = (_Float16*)(ws + OFF_W1S);
    _Float16* w2s  = (_Float16*)(ws + OFF_W2S);
    _Float16* l_t  = (_Float16*)(ws + OFF_LT);
    _Float16* pl_t = (_Float16*)(ws + OFF_PLT);

    const bool fast = (ws_size >= NEED_FAST);

    prep_small_k<<<NB_W1 + NB_W2 + NB_L, 256, 0, stream>>>(w1, w2, lines, w1s, w2s, l_t);

    if (fast) {
        prep_planes_k<<<(3 * GRES * GRES + 255) / 256, 256, 0, stream>>>(planes, pl_t);
        tsdf_fused40_k<1><<<NPTS / TILE_M, 256, 0, stream>>>(
            xyz, planes, lines, pl_t, l_t, w1s, w2s, b1, b2, out);
    } else {
        tsdf_fused40_k<0><<<NPTS / TILE_M, 256, 0, stream>>>(
            xyz, planes, lines, pl_t, l_t, w1s, w2s, b1, b2, out);
    }
}

// Round 6
// 551.534 us; speedup vs baseline: 1.1880x; 1.0309x over previous
//
#include <hip/hip_runtime.h>
#include <cstdint>
#include <cstddef>

// ---------------------------------------------------------------------------
// TensoSDF shape renderer: tri-plane sample + embed -> MLP(129->256->129)
// R7: non-temporal line-aligned output path.
//  Evidence: FETCH pinned at 372MB (=17x pl_t size) across R1/R3/R6 -> the
//  270MB out-write stream allocates in the memory-side LLC and evicts pl_t
//  between reuses, so gathers pay HBM latency. R4's NT attempt failed only
//  because scattered per-dword NT stores RMW-amplified (WRITE 921MB).
//  Fix: stage ALL 129 out cols in LDS f32 [64][136] (stride 136 -> quad rows
//  on bank sets {0,8,16,24}, max 2-way = free), then NT burst-copy 8256
//  contiguous dwords = 258 full aligned 128B lines per block. No partial
//  lines -> no RMW; no LLC allocation -> pl_t stays resident.
// Keeps: NCP=40 padded planes/lines (16B gathers), k-permuted w1/w2,
//        LDS union (mlp_in stride-168 / h swz / o stage), bounds(256,3).
// ---------------------------------------------------------------------------

using half2v  = __attribute__((ext_vector_type(2))) _Float16;
using half4   = __attribute__((ext_vector_type(4))) _Float16;
using half8   = __attribute__((ext_vector_type(8))) _Float16;
using floatx4 = __attribute__((ext_vector_type(4))) float;

#define NPTS    524288
#define GRES    300
#define NCOMP   36
#define NCP     40
#define SDFD    256
#define IN_CH   129
#define OUT_CH  129
#define TILE_M  64
#define S_INL   168     // mlp_in LDS stride in halfs
#define S_OUT   136     // out-stage LDS stride in floats (136%32=8)

// workspace layout (bytes), all 16B aligned
#define OFF_W1S 0
#define SZ_W1S  (5*4*256*8*2)               // 81920 : w1 swizzled f16 [c16][n=256][j=8]
#define OFF_W2S (OFF_W1S + SZ_W1S)
#define SZ_W2S  (8*4*144*8*2)               // 73728 : w2 swizzled f16
#define OFF_LT  (OFF_W2S + SZ_W2S)
#define SZ_LT   (3*GRES*NCP*2)              // 72000 : lines ch-last padded f16
#define OFF_PLT (OFF_LT + SZ_LT)
#define SZ_PLT  ((size_t)3*GRES*GRES*NCP*2) // 21.6MB: planes ch-last padded f16
#define NEED_FAST ((size_t)OFF_PLT + SZ_PLT)

// ---- prep kernels ---------------------------------------------------------

__global__ void prep_planes_k(const float* __restrict__ planes, _Float16* __restrict__ pl_t) {
    int idx = blockIdx.x * 256 + threadIdx.x;           // (m*300+y)*300+x
    if (idx >= 3 * GRES * GRES) return;
    int x = idx % GRES; int t = idx / GRES; int y = t % GRES; int m = t / GRES;
    _Float16* dst = pl_t + (size_t)idx * NCP;
    const float* src = planes + (size_t)m * NCOMP * GRES * GRES + (size_t)y * GRES + x;
    #pragma unroll
    for (int j = 0; j < 5; ++j) {
        half8 o;
        #pragma unroll
        for (int e = 0; e < 8; ++e) {
            int c = j * 8 + e;
            o[e] = (c < NCOMP) ? (_Float16)src[(size_t)c * GRES * GRES] : (_Float16)0.f;
        }
        *(half8*)(dst + j * 8) = o;
    }
}

#define NB_W1 ((5*4*256*8 + 255)/256)      // 160
#define NB_W2 ((8*4*144*8 + 255)/256)      // 144
#define NB_L  ((3*GRES + 255)/256)         // 4
__global__ void prep_small_k(const float* __restrict__ w1, const float* __restrict__ w2,
                             const float* __restrict__ lines,
                             _Float16* __restrict__ w1s, _Float16* __restrict__ w2s,
                             _Float16* __restrict__ l_t) {
    int b = blockIdx.x;
    if (b < NB_W1) {
        int t = b * 256 + threadIdx.x;                   // < 40960 exactly
        int j = t & 7; int n = (t >> 3) & 255; int q = t >> 11;
        int k = q * 8 + j;                               // 0..159
        float v = 0.f;
        if (k < 120) {
            int m = k / 40, c = k % 40;
            if (c < NCOMP) v = w1[n * IN_CH + 21 + m * NCOMP + c];
        } else if (k < 141) {
            v = w1[n * IN_CH + (k - 120)];
        }
        w1s[t] = (_Float16)v;
    } else if (b < NB_W1 + NB_W2) {
        int t = (b - NB_W1) * 256 + threadIdx.x;
        if (t >= 8*4*144*8) return;
        int j = t & 7; int r = t >> 3; int n = r % 144; int q = r / 144;
        int k = q * 8 + j;                               // 0..255
        float v = (n < OUT_CH) ? w2[n * SDFD + k] : 0.f;
        w2s[t] = (_Float16)v;
    } else {
        int idx = (b - NB_W1 - NB_W2) * 256 + threadIdx.x;   // m*300+z
        if (idx >= 3 * GRES) return;
        int z = idx % GRES; int m = idx / GRES;
        _Float16* dst = l_t + (size_t)idx * NCP;
        const float* src = lines + ((size_t)m * NCOMP) * GRES + z;
        #pragma unroll
        for (int c = 0; c < NCOMP; ++c) dst[c] = (_Float16)src[(size_t)c * GRES];
        dst[36] = dst[37] = dst[38] = dst[39] = (_Float16)0.f;
    }
}

// ---- device helpers -------------------------------------------------------

__device__ __forceinline__ float softplus100(float z) {
    return fmaxf(z, 0.f) + __logf(1.f + __expf(-fabsf(z)));
}

__device__ __forceinline__ void plane_coords(int m, float X, float Y, float Z,
                                             int& x0, int& y0, int& z0,
                                             float& tx, float& ty, float& tz) {
    const float px = (m == 2) ? Y : X;
    const float py = (m == 0) ? Y : Z;
    const float pz = (m == 0) ? Z : ((m == 1) ? Y : X);
    float fx = (px + 1.f) * 0.5f * 299.f;
    float fy = (py + 1.f) * 0.5f * 299.f;
    float fz = (pz + 1.f) * 0.5f * 299.f;
    x0 = (int)floorf(fx); x0 = x0 < 0 ? 0 : (x0 > 298 ? 298 : x0);
    y0 = (int)floorf(fy); y0 = y0 < 0 ? 0 : (y0 > 298 ? 298 : y0);
    z0 = (int)floorf(fz); z0 = z0 < 0 ? 0 : (z0 > 298 ? 298 : z0);
    tx = fx - (float)x0; ty = fy - (float)y0; tz = fz - (float)z0;
}

// fast gather: NCP=40 channel-last layout; corner-pair = 160B contiguous
__device__ __forceinline__ void plane_gather_fast(
    int m, float X, float Y, float Z,
    const _Float16* __restrict__ pl_t, const _Float16* __restrict__ l_t,
    half8 f[5])
{
    int x0, y0, z0; float tx, ty, tz;
    plane_coords(m, X, Y, Z, x0, y0, z0, tx, ty, tz);
    const _Float16 h00 = (_Float16)((1.f - tx) * (1.f - ty));
    const _Float16 h01 = (_Float16)(tx * (1.f - ty));
    const _Float16 h10 = (_Float16)((1.f - tx) * ty);
    const _Float16 h11 = (_Float16)(tx * ty);
    const _Float16 hl0 = (_Float16)(1.f - tz), hl1 = (_Float16)tz;
    const half8 W00 = {h00,h00,h00,h00,h00,h00,h00,h00};
    const half8 W01 = {h01,h01,h01,h01,h01,h01,h01,h01};
    const half8 W10 = {h10,h10,h10,h10,h10,h10,h10,h10};
    const half8 W11 = {h11,h11,h11,h11,h11,h11,h11,h11};
    const half8 WL0 = {hl0,hl0,hl0,hl0,hl0,hl0,hl0,hl0};
    const half8 WL1 = {hl1,hl1,hl1,hl1,hl1,hl1,hl1,hl1};
    const _Float16* r0 = pl_t + ((size_t)(m * GRES + y0) * GRES + x0) * NCP;  // (y0,x0|x0+1)
    const _Float16* r1 = r0 + (size_t)GRES * NCP;                              // (y0+1, ...)
    const _Float16* lb = l_t + (size_t)(m * GRES + z0) * NCP;                  // (z0|z0+1)
    half8 a0[10], a1[10], al[10];
    #pragma unroll
    for (int j = 0; j < 10; ++j) a0[j] = *(const half8*)(r0 + 8 * j);
    #pragma unroll
    for (int j = 0; j < 10; ++j) a1[j] = *(const half8*)(r1 + 8 * j);
    half8 pf[5];
    #pragma unroll
    for (int j = 0; j < 5; ++j)
        pf[j] = a0[j] * W00 + a0[j + 5] * W01 + a1[j] * W10 + a1[j + 5] * W11;
    #pragma unroll
    for (int j = 0; j < 10; ++j) al[j] = *(const half8*)(lb + 8 * j);
    #pragma unroll
    for (int j = 0; j < 5; ++j) {
        half8 lf = al[j] * WL0 + al[j + 5] * WL1;
        f[j] = pf[j] * lf;
    }
}

// slow gather: raw f32 planes/lines (fallback when workspace too small)
__device__ __forceinline__ void plane_gather_slow(
    int m, float X, float Y, float Z,
    const float* __restrict__ planes, const float* __restrict__ lines,
    half8 f[5])
{
    int x0, y0, z0; float tx, ty, tz;
    plane_coords(m, X, Y, Z, x0, y0, z0, tx, ty, tz);
    const float w00 = (1.f - tx) * (1.f - ty), w01 = tx * (1.f - ty);
    const float w10 = (1.f - tx) * ty,         w11 = tx * ty;
    const float lw0 = 1.f - tz, lw1 = tz;
    #pragma unroll
    for (int j = 0; j < 5; ++j) f[j] = (half8){0,0,0,0,0,0,0,0};
    const float* pb = planes + (size_t)m * NCOMP * GRES * GRES;
    #pragma unroll
    for (int c = 0; c < NCOMP; ++c) {
        const float* pc = pb + (size_t)c * GRES * GRES + (size_t)y0 * GRES + x0;
        const float* lc = lines + ((size_t)m * NCOMP + c) * GRES + z0;
        float pf = pc[0] * w00 + pc[1] * w01 + pc[GRES] * w10 + pc[GRES + 1] * w11;
        float lf = lc[0] * lw0 + lc[1] * lw1;
        f[c >> 3][c & 7] = (_Float16)(pf * lf);
    }
}

// embed -> chunks c16=15..19 (k=120..159); zeros beyond k=140
__device__ __forceinline__ void embed_chunks(float X, float Y, float Z, half8 e[5]) {
    const float v3[3] = {X, Y, Z};
    _Float16 s[3][3], c[3][3];
    #pragma unroll
    for (int d = 0; d < 3; ++d) {
        float fm = 1.f;
        #pragma unroll
        for (int q = 0; q < 3; ++q) {
            const float a = v3[d] * fm;
            s[d][q] = (_Float16)__sinf(a);
            c[d][q] = (_Float16)__cosf(a);
            fm *= 2.f;
        }
    }
    const _Float16 z0 = (_Float16)0.f;
    e[0] = (half8){(_Float16)X, (_Float16)Y, (_Float16)Z, s[0][0], s[0][1], s[0][2], s[1][0], s[1][1]};
    e[1] = (half8){s[1][2], s[2][0], s[2][1], s[2][2], c[0][0], c[0][1], c[0][2], c[1][0]};
    e[2] = (half8){c[1][1], c[1][2], c[2][0], c[2][1], c[2][2], z0, z0, z0};
    e[3] = (half8){z0,z0,z0,z0,z0,z0,z0,z0};
    e[4] = (half8){z0,z0,z0,z0,z0,z0,z0,z0};
}

// ---- fused kernel ---------------------------------------------------------
// LDS: single 34816B union buffer, three lifetimes:
//   A (phase1/layer1): mlp_in [64][S_INL=168] f16, 21504B
//   B (epilogue1/layer2): h [64][256] f16 XOR-swz (row&7)<<3, 32768B
//   C (epilogue2): out stage [64][S_OUT=136] f32, 34816B
// bounds(256,3): keep VGPR headroom for gather ILP (R4/R5: tighter bounds
// collapsed VGPR to 48/64 and serialized the 30-load gather).

template <int FASTMODE>
__global__ __launch_bounds__(256, 3)
void tsdf_fused40_k(const float* __restrict__ xyz,
                    const float* __restrict__ planes, const float* __restrict__ lines,
                    const _Float16* __restrict__ pl_t, const _Float16* __restrict__ l_t,
                    const _Float16* __restrict__ w1s, const _Float16* __restrict__ w2s,
                    const float* __restrict__ b1, const float* __restrict__ b2,
                    float* __restrict__ out)
{
    __shared__ _Float16 lds_u[TILE_M * 272];           // 34816 B union
    _Float16* mlp_lds = lds_u;                         // [64][S_INL]
    _Float16* h_lds   = lds_u;                         // [64][256] swz
    const int tid = threadIdx.x, blk = blockIdx.x;

    // ---------------- phase 1: sampling + embed into LDS -------------------
    {
        const int p = tid >> 2, sub = tid & 3;
        const size_t gp = (size_t)blk * TILE_M + p;
        const float X = xyz[gp * 3 + 0];
        const float Y = xyz[gp * 3 + 1];
        const float Z = xyz[gp * 3 + 2];
        half8 f[5];
        int c0;
        if (sub < 3) {
            if (FASTMODE) plane_gather_fast(sub, X, Y, Z, pl_t, l_t, f);
            else          plane_gather_slow(sub, X, Y, Z, planes, lines, f);
            c0 = sub * 5;
        } else {
            embed_chunks(X, Y, Z, f);
            c0 = 15;
        }
        #pragma unroll
        for (int j = 0; j < 5; ++j)
            *(half8*)&mlp_lds[p * S_INL + (c0 + j) * 8] = f[j];
    }
    __syncthreads();

    const int lane = tid & 63, wv = tid >> 6, l15 = lane & 15, quad = lane >> 4;

    // ---------------- layer 1: [64x160] @ [160x256] -> h -------------------
    floatx4 acc1[4][4];
    #pragma unroll
    for (int mt = 0; mt < 4; ++mt)
        #pragma unroll
        for (int nt = 0; nt < 4; ++nt)
            acc1[mt][nt] = (floatx4){0.f, 0.f, 0.f, 0.f};

    #pragma unroll
    for (int s = 0; s < 5; ++s) {
        half8 a[4], b[4];
        #pragma unroll
        for (int mt = 0; mt < 4; ++mt)
            a[mt] = *(const half8*)&mlp_lds[(mt * 16 + l15) * S_INL + s * 32 + quad * 8];
        #pragma unroll
        for (int nt = 0; nt < 4; ++nt)
            b[nt] = *(const half8*)(w1s + ((size_t)((s * 4 + quad) * 256) + wv * 64 + nt * 16 + l15) * 8);
        #pragma unroll
        for (int mt = 0; mt < 4; ++mt)
            #pragma unroll
            for (int nt = 0; nt < 4; ++nt)
                acc1[mt][nt] = __builtin_amdgcn_mfma_f32_16x16x32_f16(a[mt], b[nt], acc1[mt][nt], 0, 0, 0);
    }
    // all mlp_lds reads done; barrier before overwriting the union with h
    __syncthreads();

    // epilogue 1: softplus(100z)/100, write h (f16) to swizzled LDS
    #pragma unroll
    for (int nt = 0; nt < 4; ++nt) {
        const int n = wv * 64 + nt * 16 + l15;
        const float bias = b1[n];
        #pragma unroll
        for (int mt = 0; mt < 4; ++mt) {
            #pragma unroll
            for (int r = 0; r < 4; ++r) {
                const int rowh = mt * 16 + quad * 4 + r;
                const float z = 100.f * (acc1[mt][nt][r] + bias);
                h_lds[(rowh * 256 + n) ^ ((rowh & 7) << 3)] = (_Float16)(softplus100(z) * 0.01f);
            }
        }
    }
    __syncthreads();

    // ---------------- layer 2: [64x256] @ [256x144] -> out -----------------
    floatx4 acc2[9];
    #pragma unroll
    for (int nt = 0; nt < 9; ++nt) acc2[nt] = (floatx4){0.f, 0.f, 0.f, 0.f};

    const int row2 = wv * 16 + l15;
    #pragma unroll
    for (int s = 0; s < 8; ++s) {
        const half8 a = *(const half8*)&h_lds[(row2 * 256 + s * 32 + quad * 8) ^ ((row2 & 7) << 3)];
        #pragma unroll
        for (int nt = 0; nt < 9; ++nt) {
            const half8 b = *(const half8*)(w2s + ((size_t)((s * 4 + quad) * 144) + nt * 16 + l15) * 8);
            acc2[nt] = __builtin_amdgcn_mfma_f32_16x16x32_f16(a, b, acc2[nt], 0, 0, 0);
        }
    }

    // epilogue 2: stage ALL 129 cols in LDS (stride 136 -> quad rows on bank
    // sets {0,8,16,24}, max 2-way = free), then NT burst-copy 8256 dwords
    // = 258 full aligned 128B lines per block (no RMW, no LLC allocation).
    __syncthreads();                                   // all h reads done
    float* o_lds = (float*)lds_u;                      // [64][S_OUT] f32
    const int m_lo = wv * 16 + quad * 4;
    #pragma unroll
    for (int nt = 0; nt < 9; ++nt) {
        const int n = nt * 16 + l15;
        if (n < OUT_CH) {
            const float bias = b2[n];
            #pragma unroll
            for (int r = 0; r < 4; ++r)
                o_lds[(m_lo + r) * S_OUT + n] = acc2[nt][r] + bias;
        }
    }
    __syncthreads();
    float* oblk = out + (size_t)blk * TILE_M * OUT_CH;
    #pragma unroll
    for (int c = 0; c < 33; ++c) {
        const int idx = c * 256 + tid;                 // 0..8255
        if (idx < TILE_M * OUT_CH) {
            const int row = idx / 129;                 // magic-div
            const int col = idx - row * 129;
            __builtin_nontemporal_store(o_lds[row * S_OUT + col], &oblk[idx]);
        }
    }
}

// ---- launch ---------------------------------------------------------------

extern "C" void kernel_launch(void* const* d_in, const int* in_sizes, int n_in,
                              void* d_out, int out_size, void* d_ws, size_t ws_size,
                              hipStream_t stream) {
    const float* xyz    = (const float*)d_in[0];
    const float* planes = (const float*)d_in[1];
    const float* lines  = (const float*)d_in[2];
    const float* w1     = (const float*)d_in[3];
    const float* b1     = (const float*)d_in[4];
    const float* w2     = (const float*)d_in[5];
    const float* b2     = (const float*)d_in[6];
    float* out = (float*)d_out;
    char* ws = (char*)d_ws;

    _Float16* w1s  = (_Float16*)(ws + OFF_W1S);
    _Float16* w2s  = (_Float16*)(ws + OFF_W2S);
    _Float16* l_t  = (_Float16*)(ws + OFF_LT);
    _Float16* pl_t = (_Float16*)(ws + OFF_PLT);

    const bool fast = (ws_size >= NEED_FAST);

    prep_small_k<<<NB_W1 + NB_W2 + NB_L, 256, 0, stream>>>(w1, w2, lines, w1s, w2s, l_t);

    if (fast) {
        prep_planes_k<<<(3 * GRES * GRES + 255) / 256, 256, 0, stream>>>(planes, pl_t);
        tsdf_fused40_k<1><<<NPTS / TILE_M, 256, 0, stream>>>(
            xyz, planes, lines, pl_t, l_t, w1s, w2s, b1, b2, out);
    } else {
        tsdf_fused40_k<0><<<NPTS / TILE_M, 256, 0, stream>>>(
            xyz, planes, lines, pl_t, l_t, w1s, w2s, b1, b2, out);
    }
}

// Round 7
// 498.286 us; speedup vs baseline: 1.3150x; 1.1069x over previous
//
#include <hip/hip_runtime.h>
#include <cstdint>
#include <cstddef>

// ---------------------------------------------------------------------------
// TensoSDF shape renderer: tri-plane sample + embed -> MLP(129->256->129)
// R8: L2-transaction reduction (model: ~74M line-requests / 300us / 8 XCD
// ~ 10.7 req/cy/L2 = the ceiling; bytes were never the bottleneck).
//  1. Task-split gather: thread=(pgroup,task), task in {plane m x chunk j}U{embed};
//     lanes j=0..4 of a plane read 80B contiguous -> intra-wave coalescing,
//     gather requests 47M -> ~12M. Also 6 loads/pt/thread (24 payload VGPR)
//     -> no VGPR-starved load batching.
//  2. Layer-2 wave ownership flipped M-slice -> N-slice: each wave owns
//     nt={w,w+4,(8 for w0)} over ALL 64 rows; w2s read once per block
//     (72KB, was 288KB) -> weight requests 24M -> ~10M.
// Keeps: NCP=40 padded planes/lines, k-permuted w1/w2, LDS union
//        (mlp_in s168 / h swz / out s136), NT line-aligned out burst,
//        bounds(256,3) for VGPR headroom.
// ---------------------------------------------------------------------------

using half2v  = __attribute__((ext_vector_type(2))) _Float16;
using half4   = __attribute__((ext_vector_type(4))) _Float16;
using half8   = __attribute__((ext_vector_type(8))) _Float16;
using floatx4 = __attribute__((ext_vector_type(4))) float;

#define NPTS    524288
#define GRES    300
#define NCOMP   36
#define NCP     40
#define SDFD    256
#define IN_CH   129
#define OUT_CH  129
#define TILE_M  64
#define S_INL   168     // mlp_in LDS stride in halfs
#define S_OUT   136     // out-stage LDS stride in floats

// workspace layout (bytes), all 16B aligned
#define OFF_W1S 0
#define SZ_W1S  (5*4*256*8*2)               // 81920 : w1 swizzled f16 [c16][n=256][j=8]
#define OFF_W2S (OFF_W1S + SZ_W1S)
#define SZ_W2S  (8*4*144*8*2)               // 73728 : w2 swizzled f16
#define OFF_LT  (OFF_W2S + SZ_W2S)
#define SZ_LT   (3*GRES*NCP*2)              // 72000 : lines ch-last padded f16
#define OFF_PLT (OFF_LT + SZ_LT)
#define SZ_PLT  ((size_t)3*GRES*GRES*NCP*2) // 21.6MB: planes ch-last padded f16
#define NEED_FAST ((size_t)OFF_PLT + SZ_PLT)

// ---- prep kernels ---------------------------------------------------------

__global__ void prep_planes_k(const float* __restrict__ planes, _Float16* __restrict__ pl_t) {
    int idx = blockIdx.x * 256 + threadIdx.x;           // (m*300+y)*300+x
    if (idx >= 3 * GRES * GRES) return;
    int x = idx % GRES; int t = idx / GRES; int y = t % GRES; int m = t / GRES;
    _Float16* dst = pl_t + (size_t)idx * NCP;
    const float* src = planes + (size_t)m * NCOMP * GRES * GRES + (size_t)y * GRES + x;
    #pragma unroll
    for (int j = 0; j < 5; ++j) {
        half8 o;
        #pragma unroll
        for (int e = 0; e < 8; ++e) {
            int c = j * 8 + e;
            o[e] = (c < NCOMP) ? (_Float16)src[(size_t)c * GRES * GRES] : (_Float16)0.f;
        }
        *(half8*)(dst + j * 8) = o;
    }
}

#define NB_W1 ((5*4*256*8 + 255)/256)      // 160
#define NB_W2 ((8*4*144*8 + 255)/256)      // 144
#define NB_L  ((3*GRES + 255)/256)         // 4
__global__ void prep_small_k(const float* __restrict__ w1, const float* __restrict__ w2,
                             const float* __restrict__ lines,
                             _Float16* __restrict__ w1s, _Float16* __restrict__ w2s,
                             _Float16* __restrict__ l_t) {
    int b = blockIdx.x;
    if (b < NB_W1) {
        int t = b * 256 + threadIdx.x;                   // < 40960 exactly
        int j = t & 7; int n = (t >> 3) & 255; int q = t >> 11;
        int k = q * 8 + j;                               // 0..159
        float v = 0.f;
        if (k < 120) {
            int m = k / 40, c = k % 40;
            if (c < NCOMP) v = w1[n * IN_CH + 21 + m * NCOMP + c];
        } else if (k < 141) {
            v = w1[n * IN_CH + (k - 120)];
        }
        w1s[t] = (_Float16)v;
    } else if (b < NB_W1 + NB_W2) {
        int t = (b - NB_W1) * 256 + threadIdx.x;
        if (t >= 8*4*144*8) return;
        int j = t & 7; int r = t >> 3; int n = r % 144; int q = r / 144;
        int k = q * 8 + j;                               // 0..255
        float v = (n < OUT_CH) ? w2[n * SDFD + k] : 0.f;
        w2s[t] = (_Float16)v;
    } else {
        int idx = (b - NB_W1 - NB_W2) * 256 + threadIdx.x;   // m*300+z
        if (idx >= 3 * GRES) return;
        int z = idx % GRES; int m = idx / GRES;
        _Float16* dst = l_t + (size_t)idx * NCP;
        const float* src = lines + ((size_t)m * NCOMP) * GRES + z;
        #pragma unroll
        for (int c = 0; c < NCOMP; ++c) dst[c] = (_Float16)src[(size_t)c * GRES];
        dst[36] = dst[37] = dst[38] = dst[39] = (_Float16)0.f;
    }
}

// ---- device helpers -------------------------------------------------------

__device__ __forceinline__ float softplus100(float z) {
    return fmaxf(z, 0.f) + __logf(1.f + __expf(-fabsf(z)));
}

__device__ __forceinline__ void plane_coords(int m, float X, float Y, float Z,
                                             int& x0, int& y0, int& z0,
                                             float& tx, float& ty, float& tz) {
    const float px = (m == 2) ? Y : X;
    const float py = (m == 0) ? Y : Z;
    const float pz = (m == 0) ? Z : ((m == 1) ? Y : X);
    float fx = (px + 1.f) * 0.5f * 299.f;
    float fy = (py + 1.f) * 0.5f * 299.f;
    float fz = (pz + 1.f) * 0.5f * 299.f;
    x0 = (int)floorf(fx); x0 = x0 < 0 ? 0 : (x0 > 298 ? 298 : x0);
    y0 = (int)floorf(fy); y0 = y0 < 0 ? 0 : (y0 > 298 ? 298 : y0);
    z0 = (int)floorf(fz); z0 = z0 < 0 ? 0 : (z0 > 298 ? 298 : z0);
    tx = fx - (float)x0; ty = fy - (float)y0; tz = fz - (float)z0;
}

// embed -> chunks c16=15..19 (k=120..159); zeros beyond k=140
__device__ __forceinline__ void embed_chunks(float X, float Y, float Z, half8 e[5]) {
    const float v3[3] = {X, Y, Z};
    _Float16 s[3][3], c[3][3];
    #pragma unroll
    for (int d = 0; d < 3; ++d) {
        float fm = 1.f;
        #pragma unroll
        for (int q = 0; q < 3; ++q) {
            const float a = v3[d] * fm;
            s[d][q] = (_Float16)__sinf(a);
            c[d][q] = (_Float16)__cosf(a);
            fm *= 2.f;
        }
    }
    const _Float16 z0 = (_Float16)0.f;
    e[0] = (half8){(_Float16)X, (_Float16)Y, (_Float16)Z, s[0][0], s[0][1], s[0][2], s[1][0], s[1][1]};
    e[1] = (half8){s[1][2], s[2][0], s[2][1], s[2][2], c[0][0], c[0][1], c[0][2], c[1][0]};
    e[2] = (half8){c[1][1], c[1][2], c[2][0], c[2][1], c[2][2], z0, z0, z0};
    e[3] = (half8){z0,z0,z0,z0,z0,z0,z0,z0};
    e[4] = (half8){z0,z0,z0,z0,z0,z0,z0,z0};
}

__device__ __forceinline__ half8 splat8(_Float16 v) {
    return (half8){v, v, v, v, v, v, v, v};
}

// ---- fused kernel ---------------------------------------------------------
// LDS: single 34816B union buffer, three lifetimes:
//   A (phase1/layer1): mlp_in [64][S_INL=168] f16, 21504B
//   B (epilogue1/layer2): h [64][256] f16 XOR-swz (row&7)<<3, 32768B
//   C (epilogue2): out stage [64][S_OUT=136] f32, 34816B
// Phase-1 thread map: tid = pgroup*16 + task; task 0..14 = plane m=task/5,
// chunk j=task%5; task 15 = embed. g-loop over 4 points (p = pgroup*4+g).
// Lanes (same pgroup, tasks j=0..4 of plane m) read 80B contiguous -> the
// vector-memory unit coalesces them into 1-2 line requests.

template <int FASTMODE>
__global__ __launch_bounds__(256, 3)
void tsdf_fused40_k(const float* __restrict__ xyz,
                    const float* __restrict__ planes, const float* __restrict__ lines,
                    const _Float16* __restrict__ pl_t, const _Float16* __restrict__ l_t,
                    const _Float16* __restrict__ w1s, const _Float16* __restrict__ w2s,
                    const float* __restrict__ b1, const float* __restrict__ b2,
                    float* __restrict__ out)
{
    __shared__ _Float16 lds_u[TILE_M * 272];           // 34816 B union
    _Float16* mlp_lds = lds_u;                         // [64][S_INL]
    _Float16* h_lds   = lds_u;                         // [64][256] swz
    const int tid = threadIdx.x, blk = blockIdx.x;

    // ---------------- phase 1: sampling + embed into LDS -------------------
    {
        const int task = tid & 15;                     // 0..14 gather, 15 embed
        const int pb4  = (tid >> 4) * 4;               // first of this thread's 4 points
        const int m    = task / 5;                     // plane (3 if embed)
        const int j    = task - m * 5;                 // chunk within plane
        const float* xb = xyz + ((size_t)blk * TILE_M + pb4) * 3;
        const floatx4 xv0 = *(const floatx4*)(xb);
        const floatx4 xv1 = *(const floatx4*)(xb + 4);
        const floatx4 xv2 = *(const floatx4*)(xb + 8);
        #pragma unroll
        for (int g = 0; g < 4; ++g) {
            const int p = pb4 + g;
            const float X = (g == 0) ? xv0[0] : (g == 1) ? xv0[3] : (g == 2) ? xv1[2] : xv2[1];
            const float Y = (g == 0) ? xv0[1] : (g == 1) ? xv1[0] : (g == 2) ? xv1[3] : xv2[2];
            const float Z = (g == 0) ? xv0[2] : (g == 1) ? xv1[1] : (g == 2) ? xv2[0] : xv2[3];
            if (task < 15) {
                int x0, y0, z0; float tx, ty, tz;
                plane_coords(m, X, Y, Z, x0, y0, z0, tx, ty, tz);
                if (FASTMODE) {
                    const half8 W00 = splat8((_Float16)((1.f - tx) * (1.f - ty)));
                    const half8 W01 = splat8((_Float16)(tx * (1.f - ty)));
                    const half8 W10 = splat8((_Float16)((1.f - tx) * ty));
                    const half8 W11 = splat8((_Float16)(tx * ty));
                    const half8 WL0 = splat8((_Float16)(1.f - tz));
                    const half8 WL1 = splat8((_Float16)tz);
                    const _Float16* r0 = pl_t + ((size_t)(m * GRES + y0) * GRES + x0) * NCP + 8 * j;
                    const _Float16* r1 = r0 + (size_t)GRES * NCP;
                    const _Float16* lb = l_t + (size_t)(m * GRES + z0) * NCP + 8 * j;
                    const half8 v00 = *(const half8*)(r0);
                    const half8 v01 = *(const half8*)(r0 + NCP);
                    const half8 v10 = *(const half8*)(r1);
                    const half8 v11 = *(const half8*)(r1 + NCP);
                    const half8 l0  = *(const half8*)(lb);
                    const half8 l1  = *(const half8*)(lb + NCP);
                    const half8 pf = v00 * W00 + v01 * W01 + v10 * W10 + v11 * W11;
                    const half8 lf = l0 * WL0 + l1 * WL1;
                    *(half8*)&mlp_lds[p * S_INL + task * 8] = pf * lf;
                } else {
                    const float w00 = (1.f - tx) * (1.f - ty), w01 = tx * (1.f - ty);
                    const float w10 = (1.f - tx) * ty,         w11 = tx * ty;
                    const float lw0 = 1.f - tz, lw1 = tz;
                    half8 f;
                    #pragma unroll
                    for (int e = 0; e < 8; ++e) {
                        const int c = j * 8 + e;
                        float v = 0.f;
                        if (c < NCOMP) {
                            const float* pc = planes + ((size_t)(m * NCOMP + c) * GRES + y0) * GRES + x0;
                            const float* lc = lines + ((size_t)m * NCOMP + c) * GRES + z0;
                            const float pfv = pc[0] * w00 + pc[1] * w01 + pc[GRES] * w10 + pc[GRES + 1] * w11;
                            v = pfv * (lc[0] * lw0 + lc[1] * lw1);
                        }
                        f[e] = (_Float16)v;
                    }
                    *(half8*)&mlp_lds[p * S_INL + task * 8] = f;
                }
            } else {
                half8 e[5];
                embed_chunks(X, Y, Z, e);
                #pragma unroll
                for (int jj = 0; jj < 5; ++jj)
                    *(half8*)&mlp_lds[p * S_INL + (15 + jj) * 8] = e[jj];
            }
        }
    }
    __syncthreads();

    const int lane = tid & 63, wv = tid >> 6, l15 = lane & 15, quad = lane >> 4;

    // ---------------- layer 1: [64x160] @ [160x256] -> h -------------------
    // wave w owns cols w*64..w*64+63 for ALL 64 rows (N-slice, reads its
    // w1s slice exactly once).
    floatx4 acc1[4][4];
    #pragma unroll
    for (int mt = 0; mt < 4; ++mt)
        #pragma unroll
        for (int nt = 0; nt < 4; ++nt)
            acc1[mt][nt] = (floatx4){0.f, 0.f, 0.f, 0.f};

    #pragma unroll
    for (int s = 0; s < 5; ++s) {
        half8 a[4], b[4];
        #pragma unroll
        for (int mt = 0; mt < 4; ++mt)
            a[mt] = *(const half8*)&mlp_lds[(mt * 16 + l15) * S_INL + s * 32 + quad * 8];
        #pragma unroll
        for (int nt = 0; nt < 4; ++nt)
            b[nt] = *(const half8*)(w1s + ((size_t)((s * 4 + quad) * 256) + wv * 64 + nt * 16 + l15) * 8);
        #pragma unroll
        for (int mt = 0; mt < 4; ++mt)
            #pragma unroll
            for (int nt = 0; nt < 4; ++nt)
                acc1[mt][nt] = __builtin_amdgcn_mfma_f32_16x16x32_f16(a[mt], b[nt], acc1[mt][nt], 0, 0, 0);
    }
    // all mlp_lds reads done; barrier before overwriting the union with h
    __syncthreads();

    // epilogue 1: softplus(100z)/100, write h (f16) to swizzled LDS
    #pragma unroll
    for (int nt = 0; nt < 4; ++nt) {
        const int n = wv * 64 + nt * 16 + l15;
        const float bias = b1[n];
        #pragma unroll
        for (int mt = 0; mt < 4; ++mt) {
            #pragma unroll
            for (int r = 0; r < 4; ++r) {
                const int rowh = mt * 16 + quad * 4 + r;
                const float z = 100.f * (acc1[mt][nt][r] + bias);
                h_lds[(rowh * 256 + n) ^ ((rowh & 7) << 3)] = (_Float16)(softplus100(z) * 0.01f);
            }
        }
    }
    __syncthreads();

    // ---------------- layer 2: [64x256] @ [256x144] -> out -----------------
    // Flipped ownership: wave w owns col-tiles {w, w+4, (8 for w==0)} over
    // ALL rows -> w2s read once per block (72KB, was 288KB).
    const int NTL = (wv == 0) ? 3 : 2;
    floatx4 acc2[4][3];
    #pragma unroll
    for (int mt = 0; mt < 4; ++mt)
        #pragma unroll
        for (int ntl = 0; ntl < 3; ++ntl)
            acc2[mt][ntl] = (floatx4){0.f, 0.f, 0.f, 0.f};

    #pragma unroll
    for (int s = 0; s < 8; ++s) {
        half8 a[4];
        #pragma unroll
        for (int mt = 0; mt < 4; ++mt) {
            const int rowh = mt * 16 + l15;
            a[mt] = *(const half8*)&h_lds[(rowh * 256 + s * 32 + quad * 8) ^ ((rowh & 7) << 3)];
        }
        #pragma unroll
        for (int ntl = 0; ntl < 3; ++ntl) {
            if (ntl < NTL) {
                const int ntg = wv + 4 * ntl;
                const half8 b = *(const half8*)(w2s + ((size_t)((s * 4 + quad) * 144) + ntg * 16 + l15) * 8);
                #pragma unroll
                for (int mt = 0; mt < 4; ++mt)
                    acc2[mt][ntl] = __builtin_amdgcn_mfma_f32_16x16x32_f16(a[mt], b, acc2[mt][ntl], 0, 0, 0);
            }
        }
    }

    // epilogue 2: stage all 129 cols in LDS f32 [64][S_OUT], then NT
    // burst-copy 8256 contiguous dwords = 258 full aligned 128B lines.
    __syncthreads();                                   // all h reads done
    float* o_lds = (float*)lds_u;                      // [64][S_OUT] f32
    #pragma unroll
    for (int ntl = 0; ntl < 3; ++ntl) {
        if (ntl < NTL) {
            const int n = (wv + 4 * ntl) * 16 + l15;
            if (n < OUT_CH) {
                const float bias = b2[n];
                #pragma unroll
                for (int mt = 0; mt < 4; ++mt) {
                    #pragma unroll
                    for (int r = 0; r < 4; ++r)
                        o_lds[(mt * 16 + quad * 4 + r) * S_OUT + n] = acc2[mt][ntl][r] + bias;
                }
            }
        }
    }
    __syncthreads();
    float* oblk = out + (size_t)blk * TILE_M * OUT_CH;
    #pragma unroll
    for (int c = 0; c < 33; ++c) {
        const int idx = c * 256 + tid;                 // 0..8255
        if (idx < TILE_M * OUT_CH) {
            const int row = idx / 129;
            const int col = idx - row * 129;
            __builtin_nontemporal_store(o_lds[row * S_OUT + col], &oblk[idx]);
        }
    }
}

// ---- launch ---------------------------------------------------------------

extern "C" void kernel_launch(void* const* d_in, const int* in_sizes, int n_in,
                              void* d_out, int out_size, void* d_ws, size_t ws_size,
                              hipStream_t stream) {
    const float* xyz    = (const float*)d_in[0];
    const float* planes = (const float*)d_in[1];
    const float* lines  = (const float*)d_in[2];
    const float* w1     = (const float*)d_in[3];
    const float* b1     = (const float*)d_in[4];
    const float* w2     = (const float*)d_in[5];
    const float* b2     = (const float*)d_in[6];
    float* out = (float*)d_out;
    char* ws = (char*)d_ws;

    _Float16* w1s  = (_Float16*)(ws + OFF_W1S);
    _Float16* w2s  = (_Float16*)(ws + OFF_W2S);
    _Float16* l_t  = (_Float16*)(ws + OFF_LT);
    _Float16* pl_t = (_Float16*)(ws + OFF_PLT);

    const bool fast = (ws_size >= NEED_FAST);

    prep_small_k<<<NB_W1 + NB_W2 + NB_L, 256, 0, stream>>>(w1, w2, lines, w1s, w2s, l_t);

    if (fast) {
        prep_planes_k<<<(3 * GRES * GRES + 255) / 256, 256, 0, stream>>>(planes, pl_t);
        tsdf_fused40_k<1><<<NPTS / TILE_M, 256, 0, stream>>>(
            xyz, planes, lines, pl_t, l_t, w1s, w2s, b1, b2, out);
    } else {
        tsdf_fused40_k<0><<<NPTS / TILE_M, 256, 0, stream>>>(
            xyz, planes, lines, pl_t, l_t, w1s, w2s, b1, b2, out);
    }
}